// Round 9
// baseline (902.380 us; speedup 1.0000x reference)
//
#include <hip/hip_runtime.h>

#define B_SZ 64
#define T_LEN 2048
#define NIN 257
#define HID 32
#define G4 128
#define NOUT 10

#define TBT 128         // rows per xproj tile
#define PAD 34
#define NSCANB 4        // 4 scan blocks x 8 waves; 16 batches per block (MFMA N)
#define NGEMMP 1024     // one tile per producer block (r7-proven drain)
#define NTILE 1024      // 16 t-tiles * 64 batches
#define TPB 16          // t-tiles per batch

#define SC_SIG  -1.44269504f   // -log2(e): sigmoid via exp2
#define SC_TANH -2.88539008f   // -2*log2(e): tanh via 2*sig(2x)-1, folded into scale

typedef float f32x4v __attribute__((ext_vector_type(4)));
typedef _Float16 f16x8v __attribute__((ext_vector_type(4 * 2)));
typedef unsigned ux4v __attribute__((ext_vector_type(4)));

// pack two f32 -> f16 pair (lo = a, hi = b), round-toward-zero
#define PKF16(dst, a, b) \
  asm("v_cvt_pkrtz_f16_f32 %0, %1, %2" : "=v"(dst) : "v"(a), "v"(b))

__device__ __forceinline__ float sig_e2(float x) {   // 1/(1+exp2(x))
  return __builtin_amdgcn_rcpf(1.f + __builtin_amdgcn_exp2f(x));
}

// ---- GEMM tile body (512 threads): writes xproj rows [t0, t0+128) of batch bb
// Output layout (floats): [g][t][m][q][c][gate]  with strides
//   gate:1  c:4  q:64  m:256  t:2048  g:T_LEN*2048
// where row' = hid*4+gate (gate-interleaved), m=hid>>2, q=hid&3, g=bb>>4, c=bb&15.
// Values pre-scaled by the activation exp2 constant (SC_TANH for gate g, else SC_SIG).
__device__ __forceinline__ void gemm_tile(
    const float* __restrict__ A, const float* __restrict__ W,
    const float* __restrict__ b_ih, const float* __restrict__ b_hh,
    float* __restrict__ C, int bb, int t0, float* sA, float* sB)
{
  const int tid = threadIdx.x;        // 0..511
  const int gt = tid & 15;            // col group: cols {gt+16j}
  const int rw = tid >> 4;            // 0..31: rows {rw+32i}
  const int bt0 = bb * T_LEN + t0;
  float acc[4][8];
#pragma unroll
  for (int i = 0; i < 4; ++i)
#pragma unroll
    for (int j = 0; j < 8; ++j) acc[i][j] = 0.f;

  for (int kc = 0; kc < 8; ++kc) {
    const int k0 = kc * 32;
    __syncthreads();
#pragma unroll
    for (int it = 0; it < 8; ++it) {
      int s = it * 512 + tid;
      int r = s >> 5, cc = s & 31;
      sA[r * PAD + cc] = A[(size_t)(bt0 + r) * NIN + k0 + cc];
      sB[r * PAD + cc] = W[(size_t)r * NIN + k0 + cc];
    }
    __syncthreads();
#pragma unroll
    for (int k2 = 0; k2 < 16; ++k2) {
      float2 a2[4], b2[8];
#pragma unroll
      for (int i = 0; i < 4; ++i)
        a2[i] = *(const float2*)&sA[(rw + 32 * i) * PAD + 2 * k2];
#pragma unroll
      for (int j = 0; j < 8; ++j)
        b2[j] = *(const float2*)&sB[(gt + 16 * j) * PAD + 2 * k2];
#pragma unroll
      for (int i = 0; i < 4; ++i)
#pragma unroll
        for (int j = 0; j < 8; ++j) {
          acc[i][j] = fmaf(a2[i].x, b2[j].x, acc[i][j]);
          acc[i][j] = fmaf(a2[i].y, b2[j].y, acc[i][j]);
        }
    }
  }
  { // k = 256 tail
    float a[4], bb2[8];
#pragma unroll
    for (int i = 0; i < 4; ++i) a[i] = A[(size_t)(bt0 + rw + 32 * i) * NIN + 256];
#pragma unroll
    for (int j = 0; j < 8; ++j) bb2[j] = W[(size_t)(gt + 16 * j) * NIN + 256];
#pragma unroll
    for (int i = 0; i < 4; ++i)
#pragma unroll
      for (int j = 0; j < 8; ++j) acc[i][j] += a[i] * bb2[j];
  }
  float bias[8], sc[8];
#pragma unroll
  for (int j = 0; j < 8; ++j) {
    const int col = gt + 16 * j;                    // hid = col&31, gate = col>>5
    bias[j] = b_ih[col] + b_hh[col];
    sc[j] = ((col >> 5) == 2) ? SC_TANH : SC_SIG;
  }
  // even j -> hid=gt (m=gt>>2), odd j -> hid=gt+16 (m=4+(gt>>2)); r index = gate = j>>1
  const size_t gbase = (size_t)(bb >> 4) * T_LEN * 2048;
  const int cc4 = (bb & 15) * 4;
  const int me = (gt >> 2) * 256 + (gt & 3) * 64 + cc4;
#pragma unroll
  for (int i = 0; i < 4; ++i) {
    const int t = t0 + rw + 32 * i;
    float* p = C + gbase + (size_t)t * 2048 + me;
    *(float4*)p = make_float4((acc[i][0] + bias[0]) * sc[0], (acc[i][2] + bias[2]) * sc[2],
                              (acc[i][4] + bias[4]) * sc[4], (acc[i][6] + bias[6]) * sc[6]);
    *(float4*)(p + 1024) = make_float4((acc[i][1] + bias[1]) * sc[1], (acc[i][3] + bias[3]) * sc[3],
                                       (acc[i][5] + bias[5]) * sc[5], (acc[i][7] + bias[7]) * sc[7]);
  }
}

// ---- Fused kernel: blocks [0,NSCANB) MFMA-scan, rest producer ----
__global__ __launch_bounds__(512) void fused(
    const float* __restrict__ A,      // specs
    const float* __restrict__ W,      // W_ih
    const float* __restrict__ b_ih,
    const float* __restrict__ b_hh,
    const float* __restrict__ W_hh,
    const float* __restrict__ W_out,
    const float* __restrict__ b_out,
    float* __restrict__ out,
    float* __restrict__ xproj,
    int* __restrict__ flags,
    int nowait)
{
  __shared__ float sA[TBT * PAD];
  __shared__ float sB[G4 * PAD];
  __shared__ _Float16 Hbuf[1024];       // 2 x [16 c][32 hid] f16, double-buffered
  __shared__ float Hf[16][HID];
  __shared__ float Lg[16][NOUT];
  const int bid = blockIdx.x;
  const int tid = threadIdx.x;

  if (bid >= NSCANB) {
    // -------- producer: one 128x128 tile per block --------
    const int p = bid - NSCANB;
    for (int idx = p; idx < NTILE; idx += NGEMMP) {
      const int ti = idx >> 6, bb = idx & 63;
      gemm_tile(A, W, b_ih, b_hh, xproj, bb, ti * TBT, sA, sB);
      __threadfence();
      __syncthreads();
      if (tid == 0)
        __hip_atomic_store(&flags[idx], 1, __ATOMIC_RELEASE, __HIP_MEMORY_SCOPE_AGENT);
    }
    return;
  }

  // -------- consumer: MFMA scan. wave mt owns M-tile mt (hids 4mt..4mt+3) ----
  __builtin_amdgcn_s_setprio(3);
  const int g  = bid;                  // batches 16g..16g+15
  const int mt = tid >> 6;             // wave index = M-tile
  const int l  = tid & 63;
  const int cB = l & 15;               // batch column (C/D/B fragments)
  const int qD = l >> 4;
  const int hidO = 4 * mt + qD;        // hid this lane owns on the D side

  // A-fragment: A[row = l&15][k = (l>>4)*8 + j] of tile mt, f16, pre-scaled.
  // global row' = 16mt + (l&15); hid = row'>>2, gate = row'&3 (interleaved layout);
  // original W_hh row = gate*32 + hid.
  f16x8v afrag;
  {
    const int arow = l & 15;
    const int ahid = 4 * mt + (arow >> 2);
    const int agate = arow & 3;
    const float asc = (agate == 2) ? SC_TANH : SC_SIG;
    const float* wr = W_hh + (size_t)(agate * HID + ahid) * HID + (l >> 4) * 8;
    float4 wv0 = *(const float4*)wr;
    float4 wv1 = *(const float4*)(wr + 4);
    unsigned u0, u1, u2, u3;
    PKF16(u0, wv0.x * asc, wv0.y * asc);
    PKF16(u1, wv0.z * asc, wv0.w * asc);
    PKF16(u2, wv1.x * asc, wv1.y * asc);
    PKF16(u3, wv1.z * asc, wv1.w * asc);
    ux4v au = {u0, u1, u2, u3};
    afrag = __builtin_bit_cast(f16x8v, au);
  }

  // zero H buffer 0; c-state starts 0
  Hbuf[tid] = (_Float16)0.f;           // 512 threads cover buf0 exactly
  __syncthreads();

  const int rbase = cB * 32 + 8 * qD;  // B-frag read: k = 8q..8q+7 of col cB
  const int wbase = cB * 32 + hidO;    // h write slot
  int bufo = 0;
  float cst = 0.f, hcur = 0.f;         // cst = SC_TANH * c_true

  auto step = [&](f32x4v xc) {
    ux4v bu = *(const ux4v*)&Hbuf[bufo + rbase];           // ds_read_b128
    f16x8v bf = __builtin_bit_cast(f16x8v, bu);
    f32x4v d = __builtin_amdgcn_mfma_f32_16x16x32_f16(afrag, bf, xc, 0, 0, 0);
    // d[r]: r=0:i 1:f 2:g 3:o (scaled pre-activations), hid=hidO, batch=cB
    float i_ = sig_e2(d[0]);
    float f_ = sig_e2(d[1]);
    float sg = sig_e2(d[2]);           // sig(2g)
    float o_ = sig_e2(d[3]);
    float m1 = i_ * (2.f * SC_TANH);
    float sh = sg - 0.5f;
    cst = fmaf(f_, cst, m1 * sh);      // SC_TANH*(f*c + i*tanh(g))
    float tt = sig_e2(cst);            // sig(2*c_true)
    hcur = fmaf(o_ + o_, tt, -o_);     // o*tanh(c)
    Hbuf[(bufo ^ 512) + wbase] = (_Float16)hcur;
    __syncthreads();
    bufo ^= 512;
  };

  const float* xbase = xproj + (size_t)g * T_LEN * 2048 +
                       (size_t)mt * 256 + qD * 64 + cB * 4;
#define LX(X, base, t4) do { \
    (X)[0] = *(const f32x4v*)((base) + (size_t)((t4) + 0) * 2048); \
    (X)[1] = *(const f32x4v*)((base) + (size_t)((t4) + 1) * 2048); \
    (X)[2] = *(const f32x4v*)((base) + (size_t)((t4) + 2) * 2048); \
    (X)[3] = *(const f32x4v*)((base) + (size_t)((t4) + 3) * 2048); \
  } while (0)

  for (int ti = 0; ti < TPB; ++ti) {
    if (!nowait) {
      const int fidx = ti * 64 + 16 * g + cB;   // lane polls its own batch's tile
      while (__hip_atomic_load(&flags[fidx], __ATOMIC_ACQUIRE,
                               __HIP_MEMORY_SCOPE_AGENT) == 0)
        __builtin_amdgcn_s_sleep(2);
    }
    const float* xt = xbase + (size_t)ti * TBT * 2048;
    f32x4v X0[4], X1[4];
    LX(X0, xt, 0);
#pragma unroll 1
    for (int u = 0; u < 16; ++u) {
      LX(X1, xt, 8 * u + 4);
      step(X0[0]); step(X0[1]); step(X0[2]); step(X0[3]);
      if (u < 15) LX(X0, xt, 8 * u + 8);
      step(X1[0]); step(X1[1]); step(X1[2]); step(X1[3]);
    }
  }

  // head: logits = relu(h) @ W_out.T + b_out ; log_softmax (via LDS, f32 h)
  Hf[cB][hidO] = fmaxf(hcur, 0.f);
  __syncthreads();
  if (tid < 16 * NOUT) {
    const int cb = tid / NOUT, n = tid - cb * NOUT;
    float lg = b_out[n];
#pragma unroll
    for (int j = 0; j < HID; ++j) lg += Hf[cb][j] * W_out[n * HID + j];
    Lg[cb][n] = lg;
  }
  __syncthreads();
  if (tid < 16 * NOUT) {
    const int cb = tid / NOUT, n = tid - cb * NOUT;
    float mx = -1e30f;
#pragma unroll
    for (int k = 0; k < NOUT; ++k) mx = fmaxf(mx, Lg[cb][k]);
    float ss = 0.f;
#pragma unroll
    for (int k = 0; k < NOUT; ++k)
      ss += __builtin_amdgcn_exp2f(1.44269504089f * (Lg[cb][k] - mx));
    out[(16 * g + cb) * NOUT + n] =
        Lg[cb][n] - mx - 0.69314718056f * __builtin_amdgcn_logf(ss);
  }
}

// ---- fallback standalone GEMM (serial path if ws too small for flags) ----
__global__ __launch_bounds__(512) void xproj_gemm(
    const float* __restrict__ A, const float* __restrict__ W,
    const float* __restrict__ b_ih, const float* __restrict__ b_hh,
    float* __restrict__ C)
{
  __shared__ float sA[TBT * PAD];
  __shared__ float sB[G4 * PAD];
  const int idx = blockIdx.x;
  const int ti = idx >> 6, bb = idx & 63;
  gemm_tile(A, W, b_ih, b_hh, C, bb, ti * TBT, sA, sB);
}

extern "C" void kernel_launch(void* const* d_in, const int* in_sizes, int n_in,
                              void* d_out, int out_size, void* d_ws, size_t ws_size,
                              hipStream_t stream) {
  const float* specs = (const float*)d_in[0];
  const float* W_ih  = (const float*)d_in[1];
  const float* W_hh  = (const float*)d_in[2];
  const float* b_ih  = (const float*)d_in[3];
  const float* b_hh  = (const float*)d_in[4];
  const float* W_out = (const float*)d_in[5];
  const float* b_out = (const float*)d_in[6];
  float* outp  = (float*)d_out;
  float* xproj = (float*)d_ws;                       // 64 MB
  const size_t xbytes = (size_t)B_SZ * T_LEN * G4 * 4;

  if (ws_size >= xbytes + NTILE * sizeof(int)) {
    int* flags = (int*)((char*)d_ws + xbytes);
    (void)hipMemsetAsync(flags, 0, NTILE * sizeof(int), stream);
    fused<<<NSCANB + NGEMMP, 512, 0, stream>>>(specs, W_ih, b_ih, b_hh, W_hh,
                                               W_out, b_out, outp, xproj, flags, 0);
  } else {
    xproj_gemm<<<NTILE, 512, 0, stream>>>(specs, W_ih, b_ih, b_hh, xproj);
    fused<<<NSCANB, 512, 0, stream>>>(specs, W_ih, b_ih, b_hh, W_hh,
                                      W_out, b_out, outp, xproj, (int*)xproj /*unused*/, 1);
  }
}

// Round 10
// 514.385 us; speedup vs baseline: 1.7543x; 1.7543x over previous
//
#include <hip/hip_runtime.h>

#define B_SZ 64
#define T_LEN 2048
#define NIN 257
#define HID 32
#define G4 128
#define NOUT 10

#define TBT 128         // rows per xproj tile
#define PAD 34
#define CH 8
#define NSCAN 64
#define NGEMMP 1024     // one tile per producer block (r7-proven fast drain)
#define NTILE 1024      // 16 t-tiles * 64 batches
#define TPB 16          // t-tiles per batch

#define SC_SIG  -1.44269504f   // -log2(e): sigmoid via exp2
#define SC_TANH -2.88539008f   // -2*log2(e): tanh via 2*sig(2x)-1, fold into scale

typedef int v2i __attribute__((ext_vector_type(2)));
typedef unsigned long long u64;

// f16-pair GEMV ops (v_pk_*_f16 = full fp16 packed rate; hp broadcast from SGPR)
#define PKMUL16(d, w, hpk) \
  asm("v_pk_mul_f16 %0, %1, %2" : "=v"(d) : "v"(w), "s"(hpk))
#define PKFMA16(acc, w, hpk) \
  asm("v_pk_fma_f16 %0, %1, %2, %0" : "+v"(acc) : "v"(w), "s"(hpk))
#define PKADD16(d, a, b) \
  asm("v_pk_add_f16 %0, %1, %2" : "=v"(d) : "v"(a), "v"(b))
// acc(f32) += u.lo + u.hi  via dot2 with (1.0h,1.0h): folds h-sum + exact-f32 x
#define DOT2ONES(acc, u, ones) \
  asm("v_dot2_f32_f16 %0, %1, %2, %0" : "+v"(acc) : "v"(u), "s"(ones))

// pack two f32 -> f16 pair (lo = a, hi = b), round-toward-zero
#define PKF16(dst, a, b) \
  asm("v_cvt_pkrtz_f16_f32 %0, %1, %2" : "=v"(dst) : "v"(a), "v"(b))

// ---- GEMM tile body: writes xproj rows [bt0, bt0+128) ----
// Output layout: per row t, 64 float2 pairs: pair[c] = (col c, col c+64),
// pre-scaled by the activation exp2 constant for that column group.
__device__ __forceinline__ void gemm_tile(
    const float* __restrict__ A, const float* __restrict__ W,
    const float* __restrict__ b_ih, const float* __restrict__ b_hh,
    float* __restrict__ C, int bt0, float* sA, float* sB)
{
  const int tid = threadIdx.x;
  const int gt = tid & 15;
  const int btt = tid >> 4;
  float acc[8][8];
#pragma unroll
  for (int i = 0; i < 8; ++i)
#pragma unroll
    for (int j = 0; j < 8; ++j) acc[i][j] = 0.f;

  for (int kc = 0; kc < 8; ++kc) {
    const int k0 = kc * 32;
    __syncthreads();
#pragma unroll
    for (int i = 0; i < 16; ++i) {
      int s = i * 256 + tid;
      int r = s >> 5, cc = s & 31;
      sA[r * PAD + cc] = A[(size_t)(bt0 + r) * NIN + k0 + cc];
      sB[r * PAD + cc] = W[(size_t)r * NIN + k0 + cc];
    }
    __syncthreads();
#pragma unroll
    for (int k2 = 0; k2 < 16; ++k2) {
      float2 a2[8], b2[8];
#pragma unroll
      for (int i = 0; i < 8; ++i)
        a2[i] = *(const float2*)&sA[(btt + 16 * i) * PAD + 2 * k2];
#pragma unroll
      for (int j = 0; j < 8; ++j)
        b2[j] = *(const float2*)&sB[(gt + 16 * j) * PAD + 2 * k2];
#pragma unroll
      for (int i = 0; i < 8; ++i)
#pragma unroll
        for (int j = 0; j < 8; ++j) {
          acc[i][j] = fmaf(a2[i].x, b2[j].x, acc[i][j]);
          acc[i][j] = fmaf(a2[i].y, b2[j].y, acc[i][j]);
        }
    }
  }
  { // k = 256 tail
    float a[8], bb[8];
#pragma unroll
    for (int i = 0; i < 8; ++i) a[i] = A[(size_t)(bt0 + btt + 16 * i) * NIN + 256];
#pragma unroll
    for (int j = 0; j < 8; ++j) bb[j] = W[(size_t)(gt + 16 * j) * NIN + 256];
#pragma unroll
    for (int i = 0; i < 8; ++i)
#pragma unroll
      for (int j = 0; j < 8; ++j) acc[i][j] += a[i] * bb[j];
  }
  float bias[8], sc[8];
  int off[8];
#pragma unroll
  for (int j = 0; j < 8; ++j) {
    const int col = gt + 16 * j;
    bias[j] = b_ih[col] + b_hh[col];
    sc[j] = ((col >> 5) == 2) ? SC_TANH : SC_SIG;   // g-columns get tanh fold
    off[j] = ((col & 63) << 1) + (col >> 6);        // paired layout
  }
#pragma unroll
  for (int i = 0; i < 8; ++i) {
    size_t row = (size_t)(bt0 + btt + 16 * i) * G4;
#pragma unroll
    for (int j = 0; j < 8; ++j) C[row + off[j]] = (acc[i][j] + bias[j]) * sc[j];
  }
}

// ---- Fused kernel: blocks [0,64) scan, [64,64+NGEMMP) producer ----
__global__ __launch_bounds__(256) void fused(
    const float* __restrict__ A,      // specs
    const float* __restrict__ W,      // W_ih
    const float* __restrict__ b_ih,
    const float* __restrict__ b_hh,
    const float* __restrict__ W_hh,
    const float* __restrict__ W_out,
    const float* __restrict__ b_out,
    float* __restrict__ out,
    float* __restrict__ xproj,
    int* __restrict__ flags,
    int nowait)
{
  __shared__ float sA[TBT * PAD];
  __shared__ float sB[G4 * PAD];
  const int bid = blockIdx.x;

  if (bid >= NSCAN) {
    // -------- producer: one tile per block, tile-major (ti*64 + b) --------
    const int p = bid - NSCAN;
    for (int idx = p; idx < NTILE; idx += NGEMMP) {
      const int ti = idx >> 6, bb = idx & 63;
      const int bt0 = bb * T_LEN + ti * TBT;
      gemm_tile(A, W, b_ih, b_hh, xproj, bt0, sA, sB);
      __threadfence();
      __syncthreads();
      if (threadIdx.x == 0)
        __hip_atomic_store(&flags[idx], 1, __ATOMIC_RELEASE, __HIP_MEMORY_SCOPE_AGENT);
    }
    return;
  }

  // -------- consumer: LSTM scan, one wave per batch element --------
  if (threadIdx.x >= 64) return;
  __builtin_amdgcn_s_setprio(3);
  const int b = bid;
  const int l = threadIdx.x;

  // f16-pair packed recurrent weights, PRE-SCALED by activation exp2 consts:
  // wA[k] = f16(W_hh[l][2k]*sA, W_hh[l][2k+1]*sA), sA = SC_SIG (i/f rows)
  // wB[k] = same for row l+64 with SC_TANH (g rows, l<32) / SC_SIG (o rows)
  const float wsB = (l < HID) ? SC_TANH : SC_SIG;
  unsigned wA[16], wB[16];
#pragma unroll
  for (int j = 0; j < 16; j += 2) {
    float4 v0 = *(const float4*)&W_hh[l * HID + 2 * j];
    PKF16(wA[j],     v0.x * SC_SIG, v0.y * SC_SIG);
    PKF16(wA[j + 1], v0.z * SC_SIG, v0.w * SC_SIG);
    float4 v1 = *(const float4*)&W_hh[(l + 64) * HID + 2 * j];
    PKF16(wB[j],     v1.x * wsB, v1.y * wsB);
    PKF16(wB[j + 1], v1.z * wsB, v1.w * wsB);
  }
  const unsigned sONES = 0x3C003C00u;  // (1.0h, 1.0h) for horizontal-sum dot

  float c = 0.f, h = 0.f;          // c holds SC_TANH * c_true (pre-scaled)
  unsigned hp[16];                 // h broadcast as f16 pairs (SGPRs)
#pragma unroll
  for (int k = 0; k < 16; ++k) hp[k] = 0u;

  const float2* xb2 = (const float2*)(xproj + (size_t)b * T_LEN * G4);

  auto step = [&](float xa, float xg) {
    // f16-rate GEMV: 4 independent pk chains of depth 4 per gate (mul heads,
    // no zero-init), f16x2 partial sums; horizontal fold + exact-f32 x via
    // one dot2-with-ones per gate.
    unsigned uA0, uA1, uA2, uA3, uB0, uB1, uB2, uB3;
    PKMUL16(uA0, wA[0],  hp[0]);
    PKMUL16(uA1, wA[4],  hp[4]);
    PKMUL16(uA2, wA[8],  hp[8]);
    PKMUL16(uA3, wA[12], hp[12]);
    PKMUL16(uB0, wB[0],  hp[0]);
    PKMUL16(uB1, wB[4],  hp[4]);
    PKMUL16(uB2, wB[8],  hp[8]);
    PKMUL16(uB3, wB[12], hp[12]);
#pragma unroll
    for (int j = 1; j < 4; ++j) {
      PKFMA16(uA0, wA[j],      hp[j]);
      PKFMA16(uA1, wA[4 + j],  hp[4 + j]);
      PKFMA16(uA2, wA[8 + j],  hp[8 + j]);
      PKFMA16(uA3, wA[12 + j], hp[12 + j]);
      PKFMA16(uB0, wB[j],      hp[j]);
      PKFMA16(uB1, wB[4 + j],  hp[4 + j]);
      PKFMA16(uB2, wB[8 + j],  hp[8 + j]);
      PKFMA16(uB3, wB[12 + j], hp[12 + j]);
    }
    unsigned rA0, rA1, rA, rB0, rB1, rB;
    PKADD16(rA0, uA0, uA1); PKADD16(rA1, uA2, uA3); PKADD16(rA, rA0, rA1);
    PKADD16(rB0, uB0, uB1); PKADD16(rB1, uB2, uB3); PKADD16(rB, rB0, rB1);
    float accA = xa, accB = xg;        // exact-f32 x path
    DOT2ONES(accA, rA, sONES);         // accA = xa + sum(rA)   (pre-scaled i/f)
    DOT2ONES(accB, rB, sONES);         // accB = xg + sum(rB)   (pre-scaled 2g/o)
    float actA = __builtin_amdgcn_rcpf(1.f + __builtin_amdgcn_exp2f(accA));
    float sB2  = __builtin_amdgcn_rcpf(1.f + __builtin_amdgcn_exp2f(accB));
    // lanes<32: prod = SC_TANH * i * tanh(g) = (2*SC_TANH*i) * (sig2g - 0.5)
    float m1 = actA * (2.f * SC_TANH);         // off critical path
    float sh = sB2 - 0.5f;
    float prod = m1 * sh;
    // measured semantics: swap(vdst=0, src=prod) -> dst_new[32+k] = prod[k]
    v2i sw = __builtin_amdgcn_permlane32_swap(0, __float_as_int(prod), false, false);
    float pr = __int_as_float(sw[0]);
    c = fmaf(actA, c, pr);                     // lanes>=32: SC_TANH*(f*c + i*g)
    float t  = __builtin_amdgcn_rcpf(1.f + __builtin_amdgcn_exp2f(c));
    float s2 = sB2 + sB2;                      // off critical path (o = sB2)
    h = fmaf(s2, t, -sB2);                     // lanes>=32: h = o*tanh(c_true)
    // broadcast h as f16 pairs: neighbor via quad-perm DPP, pack, 16 readlanes
    int hn = __builtin_amdgcn_mov_dpp(__float_as_int(h), 0xF5, 0xF, 0xF, false);
    int pk;
    PKF16(pk, h, __int_as_float(hn));          // lane 32+2k: (h[2k], h[2k+1])
#pragma unroll
    for (int k = 0; k < 16; ++k)
      hp[k] = (unsigned)__builtin_amdgcn_readlane(pk, 32 + 2 * k);
  };

  float2 X0[CH], X1[CH];
#define LOADC2(X, P) do { _Pragma("unroll") \
  for (int i = 0; i < CH; ++i) X[i] = (P)[i * 64]; } while (0)
#define STEPS(X) do { _Pragma("unroll") \
  for (int i = 0; i < CH; ++i) step(X[i].x, X[i].y); } while (0)

  for (int ti = 0; ti < TPB; ++ti) {
    if (!nowait) {
      while (__hip_atomic_load(&flags[ti * 64 + b], __ATOMIC_ACQUIRE,
                               __HIP_MEMORY_SCOPE_AGENT) == 0)
        __builtin_amdgcn_s_sleep(2);
    }
    const float2* xt = xb2 + (size_t)ti * TBT * 64 + l;
    LOADC2(X0, xt);
#pragma unroll 1
    for (int ch = 0; ch < TBT / CH; ch += 2) {
      const float2* s1 = xt + (size_t)(ch + 1) * CH * 64;
      LOADC2(X1, s1);
      STEPS(X0);
      if (ch + 2 < TBT / CH) {
        const float2* s2 = xt + (size_t)(ch + 2) * CH * 64;
        LOADC2(X0, s2);
      }
      STEPS(X1);
    }
  }

  // head: logits = relu(h) @ W_out.T + b_out ; log_softmax  (shuffle-only)
  // h here is the exact fp32 lane value (f16 was only the broadcast copy)
  float hf[HID];
#pragma unroll
  for (int k = 0; k < HID; ++k)
    hf[k] = __int_as_float(__builtin_amdgcn_readlane(__float_as_int(h), 32 + k));
  float logit = 0.f;
  if (l < NOUT) {
    logit = b_out[l];
#pragma unroll
    for (int j = 0; j < HID; ++j) logit += fmaxf(hf[j], 0.f) * W_out[l * HID + j];
  }
  float m = -1e30f;
#pragma unroll
  for (int n = 0; n < NOUT; ++n) m = fmaxf(m, __shfl(logit, n));
  float s = 0.f;
#pragma unroll
  for (int n = 0; n < NOUT; ++n)
    s += __builtin_amdgcn_exp2f(1.44269504089f * (__shfl(logit, n) - m));
  if (l < NOUT)
    out[b * NOUT + l] = logit - m - 0.69314718056f * __builtin_amdgcn_logf(s);
}

// ---- fallback standalone GEMM (serial path if ws too small for flags) ----
__global__ __launch_bounds__(256) void xproj_gemm(
    const float* __restrict__ A, const float* __restrict__ W,
    const float* __restrict__ b_ih, const float* __restrict__ b_hh,
    float* __restrict__ C)
{
  __shared__ float sA[TBT * PAD];
  __shared__ float sB[G4 * PAD];
  const int idx = blockIdx.x;
  const int ti = idx >> 6, bb = idx & 63;
  gemm_tile(A, W, b_ih, b_hh, C, bb * T_LEN + ti * TBT, sA, sB);
}

extern "C" void kernel_launch(void* const* d_in, const int* in_sizes, int n_in,
                              void* d_out, int out_size, void* d_ws, size_t ws_size,
                              hipStream_t stream) {
  const float* specs = (const float*)d_in[0];
  const float* W_ih  = (const float*)d_in[1];
  const float* W_hh  = (const float*)d_in[2];
  const float* b_ih  = (const float*)d_in[3];
  const float* b_hh  = (const float*)d_in[4];
  const float* W_out = (const float*)d_in[5];
  const float* b_out = (const float*)d_in[6];
  float* outp  = (float*)d_out;
  float* xproj = (float*)d_ws;                       // 64 MB
  const size_t xbytes = (size_t)B_SZ * T_LEN * G4 * 4;

  if (ws_size >= xbytes + NTILE * sizeof(int)) {
    int* flags = (int*)((char*)d_ws + xbytes);
    (void)hipMemsetAsync(flags, 0, NTILE * sizeof(int), stream);
    fused<<<NSCAN + NGEMMP, 256, 0, stream>>>(specs, W_ih, b_ih, b_hh, W_hh,
                                              W_out, b_out, outp, xproj, flags, 0);
  } else {
    xproj_gemm<<<NTILE, 256, 0, stream>>>(specs, W_ih, b_ih, b_hh, xproj);
    fused<<<NSCAN, 256, 0, stream>>>(specs, W_ih, b_ih, b_hh, W_hh,
                                     W_out, b_out, outp, xproj, (int*)xproj /*unused*/, 1);
  }
}